// Round 2
// 253.073 us; speedup vs baseline: 1.0172x; 1.0172x over previous
//
#include <hip/hip_runtime.h>
#include <hip/hip_bf16.h>
#include <cstdint>
#include <cstddef>

typedef __hip_bfloat16 bf16;
typedef short short8 __attribute__((ext_vector_type(8)));
typedef float f32x4 __attribute__((ext_vector_type(4)));

#define S_LEN 2048
#define DMODEL 2048
#define NQKV 6144
#define NHEADS 32
#define HDIM 64
// log2(10000)/32
#define ROPE_L2 0.4152410118609203f

__device__ __forceinline__ void async_copy16(const bf16* g, bf16* l) {
  __builtin_amdgcn_global_load_lds(
      (const __attribute__((address_space(1))) void*)g,
      (__attribute__((address_space(3))) void*)l, 16, 0, 0);
}

__device__ __forceinline__ f32x4 mfma_bf16(short8 a, short8 b, f32x4 c) {
  return __builtin_amdgcn_mfma_f32_16x16x32_bf16(a, b, c, 0, 0, 0);
}

// ---------------- fused fp32 -> bf16 convert of x, Wqkv, Wo ----------------
__global__ __launch_bounds__(256) void cvt3_kernel(const float* __restrict__ sx,
                                                   bf16* __restrict__ dx,
                                                   const float* __restrict__ sw,
                                                   bf16* __restrict__ dw,
                                                   const float* __restrict__ so,
                                                   bf16* __restrict__ dov) {
  int i = blockIdx.x * 256 + threadIdx.x;
  const float* s;
  bf16* d;
  if (i < 1048576) {
    s = sx; d = dx;
  } else if (i < 4194304) {
    s = sw; d = dw; i -= 1048576;
  } else {
    s = so; d = dov; i -= 4194304;
  }
  const float4 v = ((const float4*)s)[i];
  union { bf16 h[4]; ushort4 u; } tmp;
  tmp.h[0] = __float2bfloat16(v.x);
  tmp.h[1] = __float2bfloat16(v.y);
  tmp.h[2] = __float2bfloat16(v.z);
  tmp.h[3] = __float2bfloat16(v.w);
  ((ushort4*)d)[i] = tmp.u;
}

// ---------------- GEMM1: qkv = x @ Wqkv^T, fused RoPE epilogue ----------------
// 256x256 tile, BK=64, 8-phase schedule (T3+T4 counted vmcnt, T5 setprio).
// LDS 128 KiB STATIC: 2 bufs x {A-kk0, A-kk1, B-kk0, B-kk1} slots of 256x32 bf16.
// (static __shared__ -> no hipFuncSetAttribute / dynamic-smem launch, which is
//  suspected to have broken graph capture last round.)
// Staging keeps the verified chunk-XOR involution (bank-conflict-free reads).
// Stage stream runs 4 half-tiles ahead; vmcnt(8) waits, never 0 in steady state.
#define QKV_NT 32
#define QBAR() do { __builtin_amdgcn_s_barrier(); __builtin_amdgcn_sched_barrier(0); } while (0)
#define WAITV(n) asm volatile("s_waitcnt vmcnt(" #n ")" ::: "memory")
#define LGKM0() do { asm volatile("s_waitcnt lgkmcnt(0)" ::: "memory"); \
                     __builtin_amdgcn_sched_barrier(0); } while (0)

__global__ __launch_bounds__(512, 2) void gemm_qkv(const bf16* __restrict__ A,
                                                   const bf16* __restrict__ W,
                                                   bf16* __restrict__ q_ws,
                                                   bf16* __restrict__ k_ws,
                                                   bf16* __restrict__ v_ws) {
  __shared__ bf16 smem[65536];   // 128 KiB static LDS
  const int tid = threadIdx.x;
  const int wave = tid >> 6, lane = tid & 63;
  const int wm = wave >> 2, wn = wave & 3;
  const int m0 = blockIdx.y * 256, n0 = blockIdx.x * 256;
  const int swc = (((lane & 3) ^ ((lane >> 3) & 3)) * 8);  // staged src chunk
  const int fr = lane & 15, fq = lane >> 4;
  const int rdc = ((fq ^ ((fr >> 1) & 3)) * 8);            // swizzled read chunk
  const int srg = wave * 16 + (lane >> 2);                 // staging row in 128-row round

  auto stageA = [&](int t_, int kk_, int off_) {
#pragma unroll
    for (int rd = 0; rd < 2; ++rd)
      async_copy16(A + (size_t)(m0 + rd * 128 + srg) * DMODEL + t_ * 64 + kk_ * 32 + swc,
                   &smem[off_ + (rd * 128 + wave * 16) * 32]);
  };
  auto stageB = [&](int t_, int kk_, int off_) {
#pragma unroll
    for (int rd = 0; rd < 2; ++rd)
      async_copy16(W + (size_t)(n0 + rd * 128 + srg) * DMODEL + t_ * 64 + kk_ * 32 + swc,
                   &smem[off_ + (rd * 128 + wave * 16) * 32]);
  };

  const f32x4 zero = {0.f, 0.f, 0.f, 0.f};
  f32x4 acc[8][4];
#pragma unroll
  for (int i = 0; i < 8; ++i)
#pragma unroll
    for (int j = 0; j < 4; ++j) acc[i][j] = zero;
  short8 a[4], b[4];

  // prologue: T0 all four slots, then T1.A0/B0  (12 loads/thread)
  stageA(0, 0, 0);
  stageB(0, 0, 16384);
  stageA(0, 1, 8192);
  stageB(0, 1, 24576);
  stageA(1, 0, 32768);
  stageB(1, 0, 32768 + 16384);
  WAITV(8);   // T0.A0/B0 landed; T0.A1,B1 + T1.A0,B0 in flight
  QBAR();

#define LOAD_A(KK, MB, BC)                                                        \
  {                                                                               \
    const bf16* sA_ = &smem[(BC) * 32768 + (KK) * 8192];                          \
    _Pragma("unroll") for (int mi = 0; mi < 4; ++mi)                              \
        a[mi] = *(const short8*)&sA_[(wm * 128 + (MB) + mi * 16 + fr) * 32 + rdc];\
  }
#define LOAD_B(KK, BC)                                                            \
  {                                                                               \
    const bf16* sB_ = &smem[(BC) * 32768 + 16384 + (KK) * 8192];                  \
    _Pragma("unroll") for (int n = 0; n < 4; ++n)                                 \
        b[n] = *(const short8*)&sB_[(wn * 64 + n * 16 + fr) * 32 + rdc];          \
  }
#define MFMA16(MB)                                                                \
  __builtin_amdgcn_s_setprio(1);                                                  \
  _Pragma("unroll") for (int mi = 0; mi < 4; ++mi)                                \
      _Pragma("unroll") for (int n = 0; n < 4; ++n)                               \
          acc[(MB) / 16 + mi][n] = mfma_bf16(a[mi], b[n], acc[(MB) / 16 + mi][n]);\
  __builtin_amdgcn_s_setprio(0);

#pragma unroll 2
  for (int t = 0; t < QKV_NT; ++t) {
    const int bc = t & 1, bn = bc ^ 1;
    // ---- p0: kk0, M rows 0-63 of wave range, all N ----
    LOAD_A(0, 0, bc); LOAD_B(0, bc);
    if (t + 1 < QKV_NT) stageA(t + 1, 1, bn * 32768 + 8192);      // T(t+1).A1
    QBAR(); LGKM0();
    MFMA16(0);
    QBAR();
    // ---- p1: kk0, M rows 64-127 (reuse b) ----
    LOAD_A(0, 64, bc);
    if (t + 1 < QKV_NT) stageB(t + 1, 1, bn * 32768 + 24576);     // T(t+1).B1
    QBAR(); LGKM0();
    MFMA16(64);
    if (t < QKV_NT - 1) { WAITV(8); } else { WAITV(0); }          // T(t).A1/B1 landed
    QBAR();
    // ---- p2: kk1, M rows 64-127, all N ----
    LOAD_A(1, 64, bc); LOAD_B(1, bc);
    if (t + 2 < QKV_NT) stageA(t + 2, 0, bc * 32768);             // T(t+2).A0 (slot retired @p1)
    QBAR(); LGKM0();
    MFMA16(64);
    QBAR();
    // ---- p3: kk1, M rows 0-63 (reuse b) ----
    LOAD_A(1, 0, bc);
    if (t + 2 < QKV_NT) stageB(t + 2, 0, bc * 32768 + 16384);     // T(t+2).B0 (slot retired @p0)
    QBAR(); LGKM0();
    MFMA16(0);
    if (t < QKV_NT - 2) { WAITV(8); }                             // T(t+1).A0/B0 landed
    else if (t == QKV_NT - 2) { WAITV(4); }
    QBAR();
  }
#undef LOAD_A
#undef LOAD_B
#undef MFMA16

  // ---------------- epilogue: RoPE for Q/K, transpose-store for V ----------------
  const int colb = n0 + wn * 64;
  const int sect = colb >> 11;          // 0=q, 1=k, 2=v (wave-uniform, block-safe)
  const int h = (colb & 2047) >> 6;
  const int col = fr, rq = fq * 4;

  if (sect < 2) {
    bf16* dst = ((sect == 0) ? q_ws : k_ws) + (size_t)h * S_LEN * HDIM;
    bf16* rep = smem + wave * 1152;     // 16 rows x stride 72 (16B-aligned)
    const float f0 = exp2f(-(float)col * ROPE_L2);
    const float f1 = exp2f(-(float)(16 + col) * ROPE_L2);
    __syncthreads();
    for (int m = 0; m < 8; ++m) {
      const int base_s = m0 + wm * 128 + m * 16;
#pragma unroll
      for (int jl = 0; jl < 2; ++jl) {
        const int dh = jl * 16 + col;
        const float fr_ = (jl == 0) ? f0 : f1;
#pragma unroll
        for (int r = 0; r < 4; ++r) {
          const int srow = base_s + rq + r;
          float sn, cs;
          __sincosf((float)srow * fr_, &sn, &cs);
          const float xl = acc[m][jl][r], xh = acc[m][jl + 2][r];
          rep[(rq + r) * 72 + dh]      = __float2bfloat16(xl * cs - xh * sn);
          rep[(rq + r) * 72 + dh + 32] = __float2bfloat16(xh * cs + xl * sn);
        }
      }
#pragma unroll
      for (int p = 0; p < 2; ++p) {
        const int rr = p * 8 + (lane >> 3), ch = lane & 7;
        const uint4 vv = *(const uint4*)&rep[rr * 72 + ch * 8];
        *(uint4*)&dst[(size_t)(base_s + rr) * HDIM + ch * 8] = vv;
      }
    }
  } else {
    // V stored transposed: [h][dh][s]
    bf16* dst = v_ws + (size_t)h * HDIM * S_LEN;
    for (int j = 0; j < 4; ++j) {
      const int dh = j * 16 + col;
      for (int m = 0; m < 8; ++m) {
        const int s0 = m0 + wm * 128 + m * 16 + rq;
        union { bf16 hx[4]; uint2 u; } vk;
#pragma unroll
        for (int r = 0; r < 4; ++r) vk.hx[r] = __float2bfloat16(acc[m][j][r]);
        *(uint2*)&dst[(size_t)dh * S_LEN + s0] = vk.u;
      }
    }
  }
}

// ---------------- flash attention (causal) — proven R5 structure ----------------
// 256-thread blocks, grid 1024 = (qt LPT heavy-first) x 32 heads. 4 waves share
// K/V tiles double-buffered in LDS (global_load_lds w16, one barrier per k-tile).
// XOR chunk swizzle on staging. Transposed tile math: S^T = K·Q^T; O^T = V^T·P^T.
__global__ __launch_bounds__(256) void attn_kernel(const bf16* __restrict__ q_ws,
                                                   const bf16* __restrict__ k_ws,
                                                   const bf16* __restrict__ vt_ws,
                                                   bf16* __restrict__ attn_out) {
  const int bid = blockIdx.x;
  const int qt = 31 - (bid >> 5);      // heavy q-tiles first (LPT)
  const int h = bid & 31;

  const int tid = threadIdx.x, wave = tid >> 6, lane = tid & 63;
  const int col = lane & 15, fq = lane >> 4;
  const int q_glob = qt * 64 + wave * 16 + col;

  __shared__ bf16 Ks[2][64 * 64];
  __shared__ bf16 Vs[2][64 * 64];
  __shared__ bf16 Pl[4][16 * 72];
  bf16* pl = Pl[wave];

  const bf16* qh = q_ws + (size_t)h * S_LEN * HDIM;
  const bf16* kh = k_ws + (size_t)h * S_LEN * HDIM;
  const bf16* vh = vt_ws + (size_t)h * HDIM * S_LEN;

  const int srow = lane >> 3;
  const int slot = lane & 7;
  const int schunk = slot ^ srow;

  auto stage = [&](int kt, int buf) {
    const int k0 = kt * 64;
#pragma unroll
    for (int j = 0; j < 2; ++j) {
      const int r8 = (wave * 2 + j) * 8;
      async_copy16(kh + (size_t)(k0 + r8 + srow) * HDIM + schunk * 8,
                   &Ks[buf][r8 * 64]);
      async_copy16(vh + (size_t)(r8 + srow) * S_LEN + k0 + schunk * 8,
                   &Vs[buf][r8 * 64]);
    }
  };

  short8 qf[2];
#pragma unroll
  for (int ks = 0; ks < 2; ++ks)
    qf[ks] = *(const short8*)&qh[(size_t)q_glob * HDIM + ks * 32 + fq * 8];

  const f32x4 zero = {0.f, 0.f, 0.f, 0.f};
  f32x4 o_acc[4] = {zero, zero, zero, zero};
  float m_i = -1e30f, l_i = 0.f;

  stage(0, 0);

  for (int kt = 0; kt <= qt; ++kt) {
    const int buf = kt & 1;
    const int k0 = kt * 64;
    __syncthreads();
    if (kt < qt) stage(kt + 1, buf ^ 1);

    short8 kf[8];
#pragma unroll
    for (int n = 0; n < 4; ++n) {
      const int row = n * 16 + col;
#pragma unroll
      for (int ks = 0; ks < 2; ++ks)
        kf[n * 2 + ks] =
            *(const short8*)&Ks[buf][row * 64 + (((ks * 4 + fq) ^ (row & 7)) * 8)];
    }
    f32x4 s_acc[4] = {zero, zero, zero, zero};
#pragma unroll
    for (int n = 0; n < 4; ++n)
#pragma unroll
      for (int ks = 0; ks < 2; ++ks)
        s_acc[n] = mfma_bf16(kf[n * 2 + ks], qf[ks], s_acc[n]);

    short8 vf[8];
#pragma unroll
    for (int n = 0; n < 4; ++n) {
      const int row = n * 16 + col;
#pragma unroll
      for (int ks = 0; ks < 2; ++ks)
        vf[n * 2 + ks] =
            *(const short8*)&Vs[buf][row * 64 + (((ks * 4 + fq) ^ (row & 7)) * 8)];
    }

    if (kt == qt) {
#pragma unroll
      for (int n = 0; n < 4; ++n)
#pragma unroll
        for (int r = 0; r < 4; ++r)
          if (k0 + n * 16 + fq * 4 + r > q_glob) s_acc[n][r] = -1e30f;
    }

    float vmax = -1e30f;
#pragma unroll
    for (int n = 0; n < 4; ++n)
#pragma unroll
      for (int r = 0; r < 4; ++r) vmax = fmaxf(vmax, s_acc[n][r]);
    vmax = fmaxf(vmax, __shfl_xor(vmax, 16, 64));
    vmax = fmaxf(vmax, __shfl_xor(vmax, 32, 64));
    const float mnew = fmaxf(m_i, vmax);
    const float alpha = __expf((m_i - mnew) * 0.125f);
    m_i = mnew;

    float rs = 0.f;
#pragma unroll
    for (int n = 0; n < 4; ++n)
#pragma unroll
      for (int r = 0; r < 4; ++r) {
        const float p = __expf((s_acc[n][r] - mnew) * 0.125f);
        s_acc[n][r] = p;
        rs += p;
      }
    rs += __shfl_xor(rs, 16, 64);
    rs += __shfl_xor(rs, 32, 64);
    l_i = l_i * alpha + rs;

#pragma unroll
    for (int n = 0; n < 4; ++n)
#pragma unroll
      for (int r = 0; r < 4; ++r) o_acc[n][r] *= alpha;

#pragma unroll
    for (int n = 0; n < 4; ++n) {
      union { bf16 hx[4]; uint2 u; } pk;
#pragma unroll
      for (int r = 0; r < 4; ++r) pk.hx[r] = __float2bfloat16(s_acc[n][r]);
      *(uint2*)&pl[col * 72 + n * 16 + fq * 4] = pk.u;
    }
    short8 pa[2];
#pragma unroll
    for (int ks = 0; ks < 2; ++ks)
      pa[ks] = *(const short8*)&pl[col * 72 + ks * 32 + fq * 8];

#pragma unroll
    for (int n = 0; n < 4; ++n)
#pragma unroll
      for (int ks = 0; ks < 2; ++ks)
        o_acc[n] = mfma_bf16(vf[n * 2 + ks], pa[ks], o_acc[n]);
  }

  const float inv = 1.0f / l_i;
#pragma unroll
  for (int n = 0; n < 4; ++n) {
#pragma unroll
    for (int r = 0; r < 4; ++r) o_acc[n][r] *= inv;
    union { bf16 hx[4]; uint2 u; } ok;
#pragma unroll
    for (int r = 0; r < 4; ++r) ok.hx[r] = __float2bfloat16(o_acc[n][r]);
    *(uint2*)&attn_out[(size_t)q_glob * DMODEL + h * HDIM + n * 16 + fq * 4] = ok.u;
  }
}

// ---------------- GEMM2: out = attn @ Wo^T, fused residual+gate ----------------
// 64x128 tile (grid 512 = 2 blocks/CU) to fix grid starvation at M=N=2048.
// 4 waves; all share the 64-row A tile, wave w owns B cols w*32..w*32+31.
__global__ __launch_bounds__(256) void gemm_out(const bf16* __restrict__ A,
                                                const bf16* __restrict__ W,
                                                const float* __restrict__ xres,
                                                const float* __restrict__ gate,
                                                float* __restrict__ out) {
  constexpr int K = DMODEL;
  __shared__ bf16 As[64 * 32];
  __shared__ bf16 Bs[128 * 32];
  const int tid = threadIdx.x;
  const int wave = tid >> 6, lane = tid & 63;
  const int m0 = blockIdx.y * 64, n0 = blockIdx.x * 128;
  const int sr = lane >> 2;
  const int swc = (((lane & 3) ^ ((lane >> 3) & 3)) * 8);
  const int fr = lane & 15, fq = lane >> 4;
  const int rdc = ((fq ^ ((fr >> 1) & 3)) * 8);

  const f32x4 zero = {0.f, 0.f, 0.f, 0.f};
  f32x4 acc[4][2];
  for (int i = 0; i < 4; ++i)
    for (int j = 0; j < 2; ++j) acc[i][j] = zero;

  for (int kt = 0; kt < K; kt += 32) {
    __syncthreads();
    async_copy16(A + (size_t)(m0 + wave * 16 + sr) * K + kt + swc,
                 &As[(wave * 16) * 32]);
#pragma unroll
    for (int j = 0; j < 2; ++j)
      async_copy16(W + (size_t)(n0 + wave * 32 + j * 16 + sr) * K + kt + swc,
                   &Bs[(wave * 32 + j * 16) * 32]);
    __syncthreads();
    short8 a[4], b[2];
    for (int i = 0; i < 4; ++i)
      a[i] = *(const short8*)&As[(i * 16 + fr) * 32 + rdc];
    for (int j = 0; j < 2; ++j)
      b[j] = *(const short8*)&Bs[(wave * 32 + j * 16 + fr) * 32 + rdc];
    for (int i = 0; i < 4; ++i)
      for (int j = 0; j < 2; ++j)
        acc[i][j] = mfma_bf16(a[i], b[j], acc[i][j]);
  }

  const int col = fr, rq = fq * 4;
  for (int j = 0; j < 2; ++j) {
    const int cc = n0 + wave * 32 + j * 16 + col;
    const float g = gate[cc];
    for (int i = 0; i < 4; ++i) {
      const int base_row = m0 + i * 16 + rq;
      for (int r = 0; r < 4; ++r) {
        const size_t idx = (size_t)(base_row + r) * DMODEL + cc;
        out[idx] = xres[idx] + g * acc[i][j][r];
      }
    }
  }
}

extern "C" void kernel_launch(void* const* d_in, const int* in_sizes, int n_in,
                              void* d_out, int out_size, void* d_ws, size_t ws_size,
                              hipStream_t stream) {
  const float* x    = (const float*)d_in[0];
  const float* Wqkv = (const float*)d_in[1];
  const float* Wo   = (const float*)d_in[2];
  const float* gate = (const float*)d_in[3];
  float* out = (float*)d_out;

  char* ws = (char*)d_ws;
  const size_t MB = 1024 * 1024;
  bf16* xb      = (bf16*)(ws);                 // 8 MB   (dead after gemm_qkv)
  bf16* wqkvb   = (bf16*)(ws + 8 * MB);        // 24 MB  (dead after gemm_qkv)
  bf16* wob     = (bf16*)(ws + 32 * MB);       // 8 MB
  bf16* q_ws    = (bf16*)(ws + 40 * MB);       // 8 MB  [h][s][dh]
  bf16* k_ws    = (bf16*)(ws + 48 * MB);       // 8 MB  [h][s][dh]
  bf16* v_ws    = (bf16*)(ws + 56 * MB);       // 8 MB  [h][dh][s] (pre-transposed)
  bf16* attn_ws = (bf16*)(ws);                 // aliases xb

  cvt3_kernel<<<dim3(20480), 256, 0, stream>>>(x, xb, Wqkv, wqkvb, Wo, wob);

  gemm_qkv<<<dim3(NQKV / 256, S_LEN / 256), 512, 0, stream>>>(xb, wqkvb, q_ws, k_ws, v_ws);
  attn_kernel<<<dim3(1024), 256, 0, stream>>>(q_ws, k_ws, v_ws, attn_ws);
  gemm_out<<<dim3(DMODEL / 128, DMODEL / 64), 256, 0, stream>>>(attn_ws, wob, x, gate, out);
}

// Round 3
// 251.881 us; speedup vs baseline: 1.0220x; 1.0047x over previous
//
#include <hip/hip_runtime.h>
#include <hip/hip_bf16.h>
#include <cstdint>
#include <cstddef>

typedef __hip_bfloat16 bf16;
typedef short short8 __attribute__((ext_vector_type(8)));
typedef float f32x4 __attribute__((ext_vector_type(4)));

#define S_LEN 2048
#define DMODEL 2048
#define NQKV 6144
#define NHEADS 32
#define HDIM 64
// log2(10000)/32
#define ROPE_L2 0.4152410118609203f

__device__ __forceinline__ void async_copy16(const bf16* g, bf16* l) {
  __builtin_amdgcn_global_load_lds(
      (const __attribute__((address_space(1))) void*)g,
      (__attribute__((address_space(3))) void*)l, 16, 0, 0);
}

__device__ __forceinline__ f32x4 mfma_bf16(short8 a, short8 b, f32x4 c) {
  return __builtin_amdgcn_mfma_f32_16x16x32_bf16(a, b, c, 0, 0, 0);
}

// ---------------- fused fp32 -> bf16 convert of x, Wqkv, Wo ----------------
__global__ __launch_bounds__(256) void cvt3_kernel(const float* __restrict__ sx,
                                                   bf16* __restrict__ dx,
                                                   const float* __restrict__ sw,
                                                   bf16* __restrict__ dw,
                                                   const float* __restrict__ so,
                                                   bf16* __restrict__ dov) {
  int i = blockIdx.x * 256 + threadIdx.x;
  const float* s;
  bf16* d;
  if (i < 1048576) {
    s = sx; d = dx;
  } else if (i < 4194304) {
    s = sw; d = dw; i -= 1048576;
  } else {
    s = so; d = dov; i -= 4194304;
  }
  const float4 v = ((const float4*)s)[i];
  union { bf16 h[4]; ushort4 u; } tmp;
  tmp.h[0] = __float2bfloat16(v.x);
  tmp.h[1] = __float2bfloat16(v.y);
  tmp.h[2] = __float2bfloat16(v.z);
  tmp.h[3] = __float2bfloat16(v.w);
  ((ushort4*)d)[i] = tmp.u;
}

// ---------------- GEMM1: qkv = x @ Wqkv^T, fused RoPE epilogue ----------------
// 256x256 tile, BK=64, 8-phase schedule (T3+T4 counted vmcnt, T5 setprio).
// FROZEN this round (control): 67.1 us, MfmaUtil 30%, limited by 192/256 grid
// coverage + per-SIMD duty, not by schedule details.
#define QKV_NT 32
#define QBAR() do { __builtin_amdgcn_s_barrier(); __builtin_amdgcn_sched_barrier(0); } while (0)
#define WAITV(n) asm volatile("s_waitcnt vmcnt(" #n ")" ::: "memory")
#define LGKM0() do { asm volatile("s_waitcnt lgkmcnt(0)" ::: "memory"); \
                     __builtin_amdgcn_sched_barrier(0); } while (0)

__global__ __launch_bounds__(512, 2) void gemm_qkv(const bf16* __restrict__ A,
                                                   const bf16* __restrict__ W,
                                                   bf16* __restrict__ q_ws,
                                                   bf16* __restrict__ k_ws,
                                                   bf16* __restrict__ v_ws) {
  __shared__ bf16 smem[65536];   // 128 KiB static LDS
  const int tid = threadIdx.x;
  const int wave = tid >> 6, lane = tid & 63;
  const int wm = wave >> 2, wn = wave & 3;
  const int m0 = blockIdx.y * 256, n0 = blockIdx.x * 256;
  const int swc = (((lane & 3) ^ ((lane >> 3) & 3)) * 8);  // staged src chunk
  const int fr = lane & 15, fq = lane >> 4;
  const int rdc = ((fq ^ ((fr >> 1) & 3)) * 8);            // swizzled read chunk
  const int srg = wave * 16 + (lane >> 2);                 // staging row in 128-row round

  auto stageA = [&](int t_, int kk_, int off_) {
#pragma unroll
    for (int rd = 0; rd < 2; ++rd)
      async_copy16(A + (size_t)(m0 + rd * 128 + srg) * DMODEL + t_ * 64 + kk_ * 32 + swc,
                   &smem[off_ + (rd * 128 + wave * 16) * 32]);
  };
  auto stageB = [&](int t_, int kk_, int off_) {
#pragma unroll
    for (int rd = 0; rd < 2; ++rd)
      async_copy16(W + (size_t)(n0 + rd * 128 + srg) * DMODEL + t_ * 64 + kk_ * 32 + swc,
                   &smem[off_ + (rd * 128 + wave * 16) * 32]);
  };

  const f32x4 zero = {0.f, 0.f, 0.f, 0.f};
  f32x4 acc[8][4];
#pragma unroll
  for (int i = 0; i < 8; ++i)
#pragma unroll
    for (int j = 0; j < 4; ++j) acc[i][j] = zero;
  short8 a[4], b[4];

  // prologue: T0 all four slots, then T1.A0/B0  (12 loads/thread)
  stageA(0, 0, 0);
  stageB(0, 0, 16384);
  stageA(0, 1, 8192);
  stageB(0, 1, 24576);
  stageA(1, 0, 32768);
  stageB(1, 0, 32768 + 16384);
  WAITV(8);   // T0.A0/B0 landed; T0.A1,B1 + T1.A0,B0 in flight
  QBAR();

#define LOAD_A(KK, MB, BC)                                                        \
  {                                                                               \
    const bf16* sA_ = &smem[(BC) * 32768 + (KK) * 8192];                          \
    _Pragma("unroll") for (int mi = 0; mi < 4; ++mi)                              \
        a[mi] = *(const short8*)&sA_[(wm * 128 + (MB) + mi * 16 + fr) * 32 + rdc];\
  }
#define LOAD_B(KK, BC)                                                            \
  {                                                                               \
    const bf16* sB_ = &smem[(BC) * 32768 + 16384 + (KK) * 8192];                  \
    _Pragma("unroll") for (int n = 0; n < 4; ++n)                                 \
        b[n] = *(const short8*)&sB_[(wn * 64 + n * 16 + fr) * 32 + rdc];          \
  }
#define MFMA16(MB)                                                                \
  __builtin_amdgcn_s_setprio(1);                                                  \
  _Pragma("unroll") for (int mi = 0; mi < 4; ++mi)                                \
      _Pragma("unroll") for (int n = 0; n < 4; ++n)                               \
          acc[(MB) / 16 + mi][n] = mfma_bf16(a[mi], b[n], acc[(MB) / 16 + mi][n]);\
  __builtin_amdgcn_s_setprio(0);

#pragma unroll 2
  for (int t = 0; t < QKV_NT; ++t) {
    const int bc = t & 1, bn = bc ^ 1;
    // ---- p0: kk0, M rows 0-63 of wave range, all N ----
    LOAD_A(0, 0, bc); LOAD_B(0, bc);
    if (t + 1 < QKV_NT) stageA(t + 1, 1, bn * 32768 + 8192);      // T(t+1).A1
    QBAR(); LGKM0();
    MFMA16(0);
    QBAR();
    // ---- p1: kk0, M rows 64-127 (reuse b) ----
    LOAD_A(0, 64, bc);
    if (t + 1 < QKV_NT) stageB(t + 1, 1, bn * 32768 + 24576);     // T(t+1).B1
    QBAR(); LGKM0();
    MFMA16(64);
    if (t < QKV_NT - 1) { WAITV(8); } else { WAITV(0); }          // T(t).A1/B1 landed
    QBAR();
    // ---- p2: kk1, M rows 64-127, all N ----
    LOAD_A(1, 64, bc); LOAD_B(1, bc);
    if (t + 2 < QKV_NT) stageA(t + 2, 0, bc * 32768);             // T(t+2).A0 (slot retired @p1)
    QBAR(); LGKM0();
    MFMA16(64);
    QBAR();
    // ---- p3: kk1, M rows 0-63 (reuse b) ----
    LOAD_A(1, 0, bc);
    if (t + 2 < QKV_NT) stageB(t + 2, 0, bc * 32768 + 16384);     // T(t+2).B0 (slot retired @p0)
    QBAR(); LGKM0();
    MFMA16(0);
    if (t < QKV_NT - 2) { WAITV(8); }                             // T(t+1).A0/B0 landed
    else if (t == QKV_NT - 2) { WAITV(4); }
    QBAR();
  }
#undef LOAD_A
#undef LOAD_B
#undef MFMA16

  // ---------------- epilogue: RoPE for Q/K, transpose-store for V ----------------
  const int colb = n0 + wn * 64;
  const int sect = colb >> 11;          // 0=q, 1=k, 2=v (wave-uniform, block-safe)
  const int h = (colb & 2047) >> 6;
  const int col = fr, rq = fq * 4;

  if (sect < 2) {
    bf16* dst = ((sect == 0) ? q_ws : k_ws) + (size_t)h * S_LEN * HDIM;
    bf16* rep = smem + wave * 1152;     // 16 rows x stride 72 (16B-aligned)
    const float f0 = exp2f(-(float)col * ROPE_L2);
    const float f1 = exp2f(-(float)(16 + col) * ROPE_L2);
    __syncthreads();
    for (int m = 0; m < 8; ++m) {
      const int base_s = m0 + wm * 128 + m * 16;
#pragma unroll
      for (int jl = 0; jl < 2; ++jl) {
        const int dh = jl * 16 + col;
        const float fr_ = (jl == 0) ? f0 : f1;
#pragma unroll
        for (int r = 0; r < 4; ++r) {
          const int srow = base_s + rq + r;
          float sn, cs;
          __sincosf((float)srow * fr_, &sn, &cs);
          const float xl = acc[m][jl][r], xh = acc[m][jl + 2][r];
          rep[(rq + r) * 72 + dh]      = __float2bfloat16(xl * cs - xh * sn);
          rep[(rq + r) * 72 + dh + 32] = __float2bfloat16(xh * cs + xl * sn);
        }
      }
#pragma unroll
      for (int p = 0; p < 2; ++p) {
        const int rr = p * 8 + (lane >> 3), ch = lane & 7;
        const uint4 vv = *(const uint4*)&rep[rr * 72 + ch * 8];
        *(uint4*)&dst[(size_t)(base_s + rr) * HDIM + ch * 8] = vv;
      }
    }
  } else {
    // V stored transposed: [h][dh][s]
    bf16* dst = v_ws + (size_t)h * HDIM * S_LEN;
    for (int j = 0; j < 4; ++j) {
      const int dh = j * 16 + col;
      for (int m = 0; m < 8; ++m) {
        const int s0 = m0 + wm * 128 + m * 16 + rq;
        union { bf16 hx[4]; uint2 u; } vk;
#pragma unroll
        for (int r = 0; r < 4; ++r) vk.hx[r] = __float2bfloat16(acc[m][j][r]);
        *(uint2*)&dst[(size_t)dh * S_LEN + s0] = vk.u;
      }
    }
  }
}

// ---------------- flash attention (causal) — 128-row q-tiles, 8 waves ----------------
// grid 512 = (qt LPT heavy-first, 16 tiles) x 32 heads. 8 waves (512 thr) share
// K/V tiles double-buffered in LDS (50 KB -> 2 blocks/CU = 4 waves/SIMD).
// Per-wave math identical to proven R5 structure (16 q-rows, S^T = K*Q^T etc).
// T13 defer-max: skip o_acc rescale when tile max doesn't move m by > 8.
__global__ __launch_bounds__(512) void attn_kernel(const bf16* __restrict__ q_ws,
                                                   const bf16* __restrict__ k_ws,
                                                   const bf16* __restrict__ vt_ws,
                                                   bf16* __restrict__ attn_out) {
  const int bid = blockIdx.x;
  const int qt = 15 - (bid >> 5);      // heavy q-tiles first (LPT)
  const int h = bid & 31;

  const int tid = threadIdx.x, wave = tid >> 6, lane = tid & 63;
  const int col = lane & 15, fq = lane >> 4;
  const int q_glob = qt * 128 + wave * 16 + col;

  __shared__ bf16 Ks[2][64 * 64];
  __shared__ bf16 Vs[2][64 * 64];
  __shared__ bf16 Pl[8][16 * 72];
  bf16* pl = Pl[wave];

  const bf16* qh = q_ws + (size_t)h * S_LEN * HDIM;
  const bf16* kh = k_ws + (size_t)h * S_LEN * HDIM;
  const bf16* vh = vt_ws + (size_t)h * HDIM * S_LEN;

  const int srow = lane >> 3;
  const int slot = lane & 7;
  const int schunk = slot ^ srow;

  // 8 waves each stage one 8-row group of K and V (2 loads/thread per tile)
  auto stage = [&](int kt, int buf) {
    const int k0 = kt * 64;
    const int r8 = wave * 8;
    async_copy16(kh + (size_t)(k0 + r8 + srow) * HDIM + schunk * 8,
                 &Ks[buf][r8 * 64]);
    async_copy16(vh + (size_t)(r8 + srow) * S_LEN + k0 + schunk * 8,
                 &Vs[buf][r8 * 64]);
  };

  short8 qf[2];
#pragma unroll
  for (int ks = 0; ks < 2; ++ks)
    qf[ks] = *(const short8*)&qh[(size_t)q_glob * HDIM + ks * 32 + fq * 8];

  const f32x4 zero = {0.f, 0.f, 0.f, 0.f};
  f32x4 o_acc[4] = {zero, zero, zero, zero};
  float m_i = -1e30f, l_i = 0.f;

  stage(0, 0);

  const int lastk = 2 * qt + 1;
  for (int kt = 0; kt <= lastk; ++kt) {
    const int buf = kt & 1;
    const int k0 = kt * 64;
    __syncthreads();
    if (kt < lastk) stage(kt + 1, buf ^ 1);

    short8 kf[8];
#pragma unroll
    for (int n = 0; n < 4; ++n) {
      const int row = n * 16 + col;
#pragma unroll
      for (int ks = 0; ks < 2; ++ks)
        kf[n * 2 + ks] =
            *(const short8*)&Ks[buf][row * 64 + (((ks * 4 + fq) ^ (row & 7)) * 8)];
    }
    f32x4 s_acc[4] = {zero, zero, zero, zero};
#pragma unroll
    for (int n = 0; n < 4; ++n)
#pragma unroll
      for (int ks = 0; ks < 2; ++ks)
        s_acc[n] = mfma_bf16(kf[n * 2 + ks], qf[ks], s_acc[n]);

    short8 vf[8];
#pragma unroll
    for (int n = 0; n < 4; ++n) {
      const int row = n * 16 + col;
#pragma unroll
      for (int ks = 0; ks < 2; ++ks)
        vf[n * 2 + ks] =
            *(const short8*)&Vs[buf][row * 64 + (((ks * 4 + fq) ^ (row & 7)) * 8)];
    }

    // mask only on tiles that can cross the diagonal for this wave (uniform)
    if (k0 + 63 > qt * 128 + wave * 16) {
#pragma unroll
      for (int n = 0; n < 4; ++n)
#pragma unroll
        for (int r = 0; r < 4; ++r)
          if (k0 + n * 16 + fq * 4 + r > q_glob) s_acc[n][r] = -1e30f;
    }

    float vmax = -1e30f;
#pragma unroll
    for (int n = 0; n < 4; ++n)
#pragma unroll
      for (int r = 0; r < 4; ++r) vmax = fmaxf(vmax, s_acc[n][r]);
    vmax = fmaxf(vmax, __shfl_xor(vmax, 16, 64));
    vmax = fmaxf(vmax, __shfl_xor(vmax, 32, 64));

    // T13 defer-max: if no lane's max moved past m_i + 8, keep old m (alpha=1).
    if (!__all(vmax - m_i <= 8.0f)) {
      const float mnew = fmaxf(m_i, vmax);
      const float alpha = __expf((m_i - mnew) * 0.125f);
      l_i *= alpha;
#pragma unroll
      for (int n = 0; n < 4; ++n)
#pragma unroll
        for (int r = 0; r < 4; ++r) o_acc[n][r] *= alpha;
      m_i = mnew;
    }

    float rs = 0.f;
#pragma unroll
    for (int n = 0; n < 4; ++n)
#pragma unroll
      for (int r = 0; r < 4; ++r) {
        const float p = __expf((s_acc[n][r] - m_i) * 0.125f);
        s_acc[n][r] = p;
        rs += p;
      }
    rs += __shfl_xor(rs, 16, 64);
    rs += __shfl_xor(rs, 32, 64);
    l_i += rs;

#pragma unroll
    for (int n = 0; n < 4; ++n) {
      union { bf16 hx[4]; uint2 u; } pk;
#pragma unroll
      for (int r = 0; r < 4; ++r) pk.hx[r] = __float2bfloat16(s_acc[n][r]);
      *(uint2*)&pl[col * 72 + n * 16 + fq * 4] = pk.u;
    }
    short8 pa[2];
#pragma unroll
    for (int ks = 0; ks < 2; ++ks)
      pa[ks] = *(const short8*)&pl[col * 72 + ks * 32 + fq * 8];

#pragma unroll
    for (int n = 0; n < 4; ++n)
#pragma unroll
      for (int ks = 0; ks < 2; ++ks)
        o_acc[n] = mfma_bf16(vf[n * 2 + ks], pa[ks], o_acc[n]);
  }

  const float inv = 1.0f / l_i;
#pragma unroll
  for (int n = 0; n < 4; ++n) {
#pragma unroll
    for (int r = 0; r < 4; ++r) o_acc[n][r] *= inv;
    union { bf16 hx[4]; uint2 u; } ok;
#pragma unroll
    for (int r = 0; r < 4; ++r) ok.hx[r] = __float2bfloat16(o_acc[n][r]);
    *(uint2*)&attn_out[(size_t)q_glob * DMODEL + h * HDIM + n * 16 + fq * 4] = ok.u;
  }
}

// ---------------- GEMM2: out = attn @ Wo^T, fused residual+gate ----------------
// 64x128 tile, grid 512 (2 blocks/CU). NEW: 3-slot rotating LDS (36 KB) with
// counted vmcnt(3) — stage T+2 while computing T; steady state never drains the
// load queue to 0 (removes the old single-buffer double-full-drain per K-step).
__global__ __launch_bounds__(256) void gemm_out(const bf16* __restrict__ A,
                                                const bf16* __restrict__ W,
                                                const float* __restrict__ xres,
                                                const float* __restrict__ gate,
                                                float* __restrict__ out) {
  constexpr int K = DMODEL;
  constexpr int NT = K / 32;           // 64 K-steps
  __shared__ bf16 As[3][64 * 32];
  __shared__ bf16 Bs[3][128 * 32];
  const int tid = threadIdx.x;
  const int wave = tid >> 6, lane = tid & 63;
  const int m0 = blockIdx.y * 64, n0 = blockIdx.x * 128;
  const int sr = lane >> 2;
  const int swc = (((lane & 3) ^ ((lane >> 3) & 3)) * 8);
  const int fr = lane & 15, fq = lane >> 4;
  const int rdc = ((fq ^ ((fr >> 1) & 3)) * 8);

  auto stage = [&](int t_, int s_) {
    async_copy16(A + (size_t)(m0 + wave * 16 + sr) * K + t_ * 32 + swc,
                 &As[s_][(wave * 16) * 32]);
#pragma unroll
    for (int j = 0; j < 2; ++j)
      async_copy16(W + (size_t)(n0 + wave * 32 + j * 16 + sr) * K + t_ * 32 + swc,
                   &Bs[s_][(wave * 32 + j * 16) * 32]);
  };

  const f32x4 zero = {0.f, 0.f, 0.f, 0.f};
  f32x4 acc[4][2];
  for (int i = 0; i < 4; ++i)
    for (int j = 0; j < 2; ++j) acc[i][j] = zero;

  // prologue: slots 0 and 1 in flight (3 loads each)
  stage(0, 0);
  stage(1, 1);
  WAITV(3);       // T0 landed; T1 in flight
  QBAR();

  for (int t = 0; t < NT; ++t) {
    const int s = t % 3;
    short8 a[4], b[2];
#pragma unroll
    for (int i = 0; i < 4; ++i)
      a[i] = *(const short8*)&As[s][(i * 16 + fr) * 32 + rdc];
#pragma unroll
    for (int j = 0; j < 2; ++j)
      b[j] = *(const short8*)&Bs[s][(wave * 32 + j * 16 + fr) * 32 + rdc];
    LGKM0();                           // my reads of slot s complete (in regs)
    QBAR();                            // all waves done reading slot s-1 region
    if (t + 2 < NT) stage(t + 2, (t + 2) % 3);   // slot (t+2)%3 retired at t-1
#pragma unroll
    for (int i = 0; i < 4; ++i)
#pragma unroll
      for (int j = 0; j < 2; ++j)
        acc[i][j] = mfma_bf16(a[i], b[j], acc[i][j]);
    if (t + 1 < NT) {
      if (t + 2 < NT) { WAITV(3); }    // T(t+1) landed; T(t+2) stays in flight
      else            { WAITV(0); }    // tail: drain once
      QBAR();
    }
  }

  const int col = fr, rq = fq * 4;
  for (int j = 0; j < 2; ++j) {
    const int cc = n0 + wave * 32 + j * 16 + col;
    const float g = gate[cc];
    for (int i = 0; i < 4; ++i) {
      const int base_row = m0 + i * 16 + rq;
      for (int r = 0; r < 4; ++r) {
        const size_t idx = (size_t)(base_row + r) * DMODEL + cc;
        out[idx] = xres[idx] + g * acc[i][j][r];
      }
    }
  }
}

extern "C" void kernel_launch(void* const* d_in, const int* in_sizes, int n_in,
                              void* d_out, int out_size, void* d_ws, size_t ws_size,
                              hipStream_t stream) {
  const float* x    = (const float*)d_in[0];
  const float* Wqkv = (const float*)d_in[1];
  const float* Wo   = (const float*)d_in[2];
  const float* gate = (const float*)d_in[3];
  float* out = (float*)d_out;

  char* ws = (char*)d_ws;
  const size_t MB = 1024 * 1024;
  bf16* xb      = (bf16*)(ws);                 // 8 MB   (dead after gemm_qkv)
  bf16* wqkvb   = (bf16*)(ws + 8 * MB);        // 24 MB  (dead after gemm_qkv)
  bf16* wob     = (bf16*)(ws + 32 * MB);       // 8 MB
  bf16* q_ws    = (bf16*)(ws + 40 * MB);       // 8 MB  [h][s][dh]
  bf16* k_ws    = (bf16*)(ws + 48 * MB);       // 8 MB  [h][s][dh]
  bf16* v_ws    = (bf16*)(ws + 56 * MB);       // 8 MB  [h][dh][s] (pre-transposed)
  bf16* attn_ws = (bf16*)(ws);                 // aliases xb

  cvt3_kernel<<<dim3(20480), 256, 0, stream>>>(x, xb, Wqkv, wqkvb, Wo, wob);

  gemm_qkv<<<dim3(NQKV / 256, S_LEN / 256), 512, 0, stream>>>(xb, wqkvb, q_ws, k_ws, v_ws);
  attn_kernel<<<dim3(512), 512, 0, stream>>>(q_ws, k_ws, v_ws, attn_ws);
  gemm_out<<<dim3(DMODEL / 128, DMODEL / 64), 256, 0, stream>>>(attn_ws, wob, x, gate, out);
}